// Round 1
// baseline (579.592 us; speedup 1.0000x reference)
//
#include <hip/hip_runtime.h>
#include <math.h>

// Problem constants
#define BB 32
#define DD 512
#define TT 64
#define RR 49
#define TR 3136      // TT*RR
#define KK 64
#define OUTN 1024
#define KD 32768     // KK*DD
#define PSTR 1048576ull  // vladP part stride in floats (BB*KK*DD)

typedef float f4 __attribute__((ext_vector_type(4)));
typedef short s8 __attribute__((ext_vector_type(8)));

// Workspace layout (byte offsets, all 256-aligned)
#define OFF_ASSIGN 0ull          // bf16 assign [32][64][3136]    = 12,845,056 B
#define OFF_VLADP  12845056ull   // fp32 vladP [4][32][64][512]   = 16,777,216 B
#define OFF_VN     29622272ull   // bf16 vlad_n [32][32768]       =  2,097,152 B
#define OFF_CWB    31719424ull   // bf16 conv_w [64][512]         =     65,536 B
#define OFF_SS     31784960ull   // fp32 ss [32][64]              =      8,192 B
#define OFF_ASUM   31793152ull   // fp32 asum [32][64]            =      8,192 B
#define OFF_Y      31801344ull   // fp32 y [32][1024]             =    131,072 B
// end: 31,932,416 B (~30.5 MB)

// Cheap fp32->bf16 pack: round-half-up (+0x8000 on bits) then v_perm high-half
// pack. 6 VALU ops per 4 elements vs ~20 for full RNE emulation.
__device__ __forceinline__ unsigned long long pack4(float a, float b, float c, float d) {
    union { float f; unsigned u; } A, B, C, D;
    A.f = a; B.f = b; C.f = c; D.f = d;
    unsigned lo = __builtin_amdgcn_perm(B.u + 0x8000u, A.u + 0x8000u, 0x07060302u);
    unsigned hi = __builtin_amdgcn_perm(D.u + 0x8000u, C.u + 0x8000u, 0x07060302u);
    return (unsigned long long)lo | ((unsigned long long)hi << 32);
}

// ---------------------------------------------------------------------------
// kW: one-time conv_w fp32 -> bf16 convert (was redone by all 1568 kA blocks)
// ---------------------------------------------------------------------------
__global__ __launch_bounds__(256) void kW(const float* __restrict__ convw,
                                          unsigned short* __restrict__ cwb) {
    int idx = blockIdx.x * 256 + threadIdx.x;   // 8192 f4's total
    f4 v = *(const f4*)(convw + idx * 4);
    *(unsigned long long*)(cwb + idx * 4) = pack4(v[0], v[1], v[2], v[3]);
}

// ---------------------------------------------------------------------------
// kA: logits = conv_w @ x (MFMA bf16), softmax over k, mask, asum, assign(bf16)
// grid 32*49, block 256. Per block: 64 k x 64 p, K-loop over d=512.
// v2: A-frags straight from L2-hot bf16 global (no cw LDS), x-transpose tile
// double-buffered with 2-deep register pipeline (1 barrier/K-step), softmax sm
// aliased onto staging LDS: 52 KB -> 36.9 KB (4 blocks/CU).
// ---------------------------------------------------------------------------
__global__ __launch_bounds__(256) void kA(const float* __restrict__ x,
                                          const int* __restrict__ mask,
                                          const unsigned short* __restrict__ cwb,
                                          unsigned short* __restrict__ assign,
                                          float* __restrict__ asum) {
    __shared__ __align__(16) char smem[2 * 17408 + 2048];
    unsigned short* xT0 = (unsigned short*)smem;            // [64 p][128 d + pad]
    unsigned short* xT1 = (unsigned short*)(smem + 17408);
    float* sm   = (float*)smem;                              // aliases xT0, phase 2
    float* redM = (float*)(smem + 34816);                    // [4][64]
    float* redS = redM + 256;                                // [4][64]

    const int blk = blockIdx.x;
    const int b = blk / 49;
    const int pc = blk % 49;
    const int p0 = pc * 64;
    const int tid = threadIdx.x;
    const int lane = tid & 63;
    const int wv = tid >> 6;
    const int quad = lane >> 4;
    const int l15 = lane & 15;
    const int pq = tid & 15;
    const int dq0 = tid >> 4;   // 0..15

    const float* xb = x + (size_t)b * DD * TR + p0 + pq * 4;
    const unsigned short* cwrow = cwb + (wv * 16 + l15) * DD + quad * 8;

    f4 xr[2][4];          // x pipeline regs (one d-chunk)
    s8 afc[4], afn[4];    // A-fragments: current / next d-chunk
    f4 acc[4];
#pragma unroll
    for (int t = 0; t < 4; ++t) acc[t] = (f4){0.f, 0.f, 0.f, 0.f};

    auto XLOAD = [&](int d0) {
#pragma unroll
        for (int i = 0; i < 2; ++i) {
            const float* xp = xb + (size_t)(d0 + (dq0 + 16 * i) * 4) * TR;
            xr[i][0] = *(const f4*)(xp);
            xr[i][1] = *(const f4*)(xp + TR);
            xr[i][2] = *(const f4*)(xp + 2 * TR);
            xr[i][3] = *(const f4*)(xp + 3 * TR);
        }
    };
    auto XSTORE = [&](unsigned short* buf) {
#pragma unroll
        for (int i = 0; i < 2; ++i) {
            const int dq = dq0 + 16 * i;
#pragma unroll
            for (int jj = 0; jj < 4; ++jj) {
                const int j = (jj + pq) & 3;  // stagger to spread banks
                *(unsigned long long*)(buf + (pq * 4 + j) * 136 + dq * 4) =
                    pack4(xr[i][0][j], xr[i][1][j], xr[i][2][j], xr[i][3][j]);
            }
        }
    };
    auto ALOAD = [&](s8* af, int d0) {
#pragma unroll
        for (int ks = 0; ks < 4; ++ks)
            af[ks] = *(const s8*)(cwrow + d0 + ks * 32);
    };

    // prologue: fill buf0 with chunk 0, start loads for chunk 1
    XLOAD(0);
    ALOAD(afc, 0);
    XSTORE(xT0);
    XLOAD(128);
    __syncthreads();

#pragma unroll
    for (int dc = 0; dc < 4; ++dc) {
        unsigned short* cur = (dc & 1) ? xT1 : xT0;
        unsigned short* nxt = (dc & 1) ? xT0 : xT1;
        if (dc < 3) XSTORE(nxt);            // xr holds x(dc+1); fills OTHER buffer
        if (dc < 2) XLOAD((dc + 2) * 128);  // issue loads 2 chunks ahead
        if (dc < 3) ALOAD(afn, (dc + 1) * 128);
#pragma unroll
        for (int ks = 0; ks < 4; ++ks) {
            const int off = ks * 32 + quad * 8;
#pragma unroll
            for (int t = 0; t < 4; ++t) {
                s8 bfr = *(const s8*)(cur + (t * 16 + l15) * 136 + off);
                acc[t] = __builtin_amdgcn_mfma_f32_16x16x32_bf16(afc[ks], bfr, acc[t], 0, 0, 0);
            }
        }
        if (dc < 3) {
#pragma unroll
            for (int ks = 0; ks < 4; ++ks) afc[ks] = afn[ks];
        }
        __syncthreads();   // one barrier per K-step
    }

    // dump C/D frags to sm[k][p]: col=lane&15 (p), row=quad*4+reg (k)
#pragma unroll
    for (int t = 0; t < 4; ++t)
#pragma unroll
        for (int r = 0; r < 4; ++r)
            sm[(wv * 16 + quad * 4 + r) * 68 + t * 16 + l15] = acc[t][r];
    __syncthreads();

    // parallel softmax over k per column p: wave wv owns k in [wv*16, wv*16+16)
    const int p = lane;
    float mx = -1e30f;
#pragma unroll
    for (int i = 0; i < 16; ++i) mx = fmaxf(mx, sm[(wv * 16 + i) * 68 + p]);
    redM[wv * 64 + p] = mx;
    __syncthreads();
    mx = fmaxf(fmaxf(redM[p], redM[64 + p]), fmaxf(redM[128 + p], redM[192 + p]));
    float s = 0.f;
#pragma unroll
    for (int i = 0; i < 16; ++i) {
        float e = __expf(sm[(wv * 16 + i) * 68 + p] - mx);
        sm[(wv * 16 + i) * 68 + p] = e;
        s += e;
    }
    redS[wv * 64 + p] = s;
    __syncthreads();
    float tot = redS[p] + redS[64 + p] + redS[128 + p] + redS[192 + p];
    const int tt = (p0 + p) / RR;
    const float inv = (float)mask[b * TT + tt] / tot;
    // scale + per-k wave-reduced asum
#pragma unroll
    for (int i = 0; i < 16; ++i) {
        float v = sm[(wv * 16 + i) * 68 + p] * inv;
        sm[(wv * 16 + i) * 68 + p] = v;
        float r = v;
#pragma unroll
        for (int off = 32; off > 0; off >>= 1) r += __shfl_down(r, off, 64);
        if (lane == 0) atomicAdd(&asum[b * 64 + wv * 16 + i], r);
    }
    __syncthreads();
    // write assign bf16 [k][p]
#pragma unroll
    for (int i = 0; i < 4; ++i) {
        int lin = i * 256 + tid;
        int kr = lin >> 4;
        int pqq = lin & 15;
        f4 v = *(const f4*)(sm + kr * 68 + pqq * 4);
        *(unsigned long long*)(assign + (size_t)(b * 64 + kr) * TR + p0 + pqq * 4) =
            pack4(v[0], v[1], v[2], v[3]);
    }
}

// ---------------------------------------------------------------------------
// kB: vladP[ph][b,k,d] = sum_{p in quarter} assign[k][p]*x[d][p]  (MFMA bf16)
// part 0 additionally subtracts asum*centroid. grid 32*8*4 (was *2: 2 blk/CU
// -> 4 blk/CU), block 256. Load-ahead pipeline: pc+1 loads issued pre-barrier.
// ---------------------------------------------------------------------------
__global__ __launch_bounds__(256) void kB(const float* __restrict__ x,
                                          const unsigned short* __restrict__ assign,
                                          const float* __restrict__ asum,
                                          const float* __restrict__ cent,
                                          float* __restrict__ vladP) {
    __shared__ unsigned short as_l[64 * 72];  // [k][p-chunk 64 + pad]
    __shared__ unsigned short x_l[64 * 72];   // [d][p-chunk 64 + pad]

    const int blk = blockIdx.x;
    const int b  = blk >> 5;
    const int ds = (blk >> 2) & 7;
    const int ph = blk & 3;
    const int d0 = ds * 64;
    const int tid = threadIdx.x;
    const int lane = tid & 63;
    const int wv = tid >> 6;
    const int quad = lane >> 4;
    const int l15 = lane & 15;

    f4 acc[4];
#pragma unroll
    for (int t = 0; t < 4; ++t) acc[t] = (f4){0.f, 0.f, 0.f, 0.f};

    const int pcs = (ph * 49) >> 2;        // 0,12,24,36
    const int pce = ((ph + 1) * 49) >> 2;  // 12,24,36,49

    const int ar0 = tid >> 3, ac0 = tid & 7;   // assign staging
    const int xr0 = tid >> 4, xc0 = tid & 15;  // x staging

    s8 asr[2];
    f4 xrr[4];
    auto LOADB = [&](int pc) {
        const int pp = pc * 64;
#pragma unroll
        for (int i = 0; i < 2; ++i)
            asr[i] = *(const s8*)(assign + (size_t)(b * 64 + ar0 + i * 32) * TR + pp + ac0 * 8);
#pragma unroll
        for (int i = 0; i < 4; ++i)
            xrr[i] = *(const f4*)(x + (size_t)(b * DD + d0 + xr0 + i * 16) * TR + pp + xc0 * 4);
    };
    auto STOREB = [&]() {
#pragma unroll
        for (int i = 0; i < 2; ++i)
            *(s8*)(as_l + (ar0 + i * 32) * 72 + ac0 * 8) = asr[i];
#pragma unroll
        for (int i = 0; i < 4; ++i)
            *(unsigned long long*)(x_l + (xr0 + i * 16) * 72 + xc0 * 4) =
                pack4(xrr[i][0], xrr[i][1], xrr[i][2], xrr[i][3]);
    };

    LOADB(pcs);
    for (int pc = pcs; pc < pce; ++pc) {
        __syncthreads();
        STOREB();
        if (pc + 1 < pce) LOADB(pc + 1);   // next-tile loads fly over MFMA phase
        __syncthreads();
#pragma unroll
        for (int ks = 0; ks < 2; ++ks) {
            const int off = ks * 32 + quad * 8;
            s8 af = *(const s8*)(as_l + (wv * 16 + l15) * 72 + off);
#pragma unroll
            for (int t = 0; t < 4; ++t) {
                s8 bfr = *(const s8*)(x_l + (t * 16 + l15) * 72 + off);
                acc[t] = __builtin_amdgcn_mfma_f32_16x16x32_bf16(af, bfr, acc[t], 0, 0, 0);
            }
        }
    }
    float* vp = vladP + (size_t)ph * PSTR;
#pragma unroll
    for (int r = 0; r < 4; ++r) {
        const int k = wv * 16 + quad * 4 + r;
        float corr = (ph == 0) ? asum[b * 64 + k] : 0.f;
#pragma unroll
        for (int t = 0; t < 4; ++t) {
            const int d = d0 + t * 16 + l15;
            float v = acc[t][r];
            if (ph == 0) v -= corr * cent[k * DD + d];
            vp[(size_t)(b * 64 + k) * DD + d] = v;
        }
    }
}

// ---------------------------------------------------------------------------
// kC1: per-row sum of squares of (P0+P1+P2+P3). grid 32*8, block 256.
// ---------------------------------------------------------------------------
__global__ __launch_bounds__(256) void kC1(const float* __restrict__ vladP,
                                           float* __restrict__ ss) {
    const int blk = blockIdx.x;
    const int b = blk >> 3;
    const int ks = blk & 7;
    const int tid = threadIdx.x;
    const int kr = tid >> 5;
    const int l32 = tid & 31;
    const int k = ks * 8 + kr;
    const float* q = vladP + (size_t)(b * 64 + k) * DD;
    float s = 0.f;
#pragma unroll
    for (int i = 0; i < 4; ++i) {
        f4 a0 = *(const f4*)(q + i * 128 + l32 * 4);
        f4 a1 = *(const f4*)(q + PSTR + i * 128 + l32 * 4);
        f4 a2 = *(const f4*)(q + 2 * PSTR + i * 128 + l32 * 4);
        f4 a3 = *(const f4*)(q + 3 * PSTR + i * 128 + l32 * 4);
#pragma unroll
        for (int j = 0; j < 4; ++j) {
            float v = (a0[j] + a1[j]) + (a2[j] + a3[j]);
            s = fmaf(v, v, s);
        }
    }
    for (int off = 16; off > 0; off >>= 1) s += __shfl_down(s, off, 32);
    if (l32 == 0) ss[b * 64 + k] = s;
}

// ---------------------------------------------------------------------------
// kC2: scales = intra*global norm; write vlad_n bf16. grid 32*8, block 256.
// ---------------------------------------------------------------------------
__global__ __launch_bounds__(256) void kC2(const float* __restrict__ vladP,
                                           const float* __restrict__ ss,
                                           unsigned short* __restrict__ vn) {
    __shared__ float sc[64];
    const int blk = blockIdx.x;
    const int b = blk >> 3;
    const int js = blk & 7;
    const int tid = threadIdx.x;
    if (tid < 64) {
        float rn = sqrtf(ss[b * 64 + tid]);
        float inv = 1.f / fmaxf(rn, 1e-12f);
        float cb = rn * inv; cb = cb * cb;
        float g = cb;
        for (int off = 32; off > 0; off >>= 1) g += __shfl_down(g, off, 64);
        g = __shfl(g, 0, 64);
        float gi = 1.f / fmaxf(sqrtf(g), 1e-12f);
        sc[tid] = inv * gi;
    }
    __syncthreads();
    const float* q = vladP + (size_t)b * KD;
#pragma unroll
    for (int it = 0; it < 4; ++it) {
        int j = js * 4096 + it * 1024 + tid * 4;
        f4 a0 = *(const f4*)(q + j);
        f4 a1 = *(const f4*)(q + PSTR + j);
        f4 a2 = *(const f4*)(q + 2 * PSTR + j);
        f4 a3 = *(const f4*)(q + 3 * PSTR + j);
        float scl = sc[j >> 9];
        *(unsigned long long*)(vn + (size_t)b * KD + j) =
            pack4(((a0[0] + a1[0]) + (a2[0] + a3[0])) * scl,
                  ((a0[1] + a1[1]) + (a2[1] + a3[1])) * scl,
                  ((a0[2] + a1[2]) + (a2[2] + a3[2])) * scl,
                  ((a0[3] + a1[3]) + (a2[3] + a3[3])) * scl);
    }
}

// ---------------------------------------------------------------------------
// kD: y[b,o] += vlad_n @ red_w^T (MFMA bf16). grid 16 o-tiles * 32 j-splits
// (was 16: 1 blk/CU), block 256. LDS 50KB->26KB; load-ahead pipeline.
// ---------------------------------------------------------------------------
__global__ __launch_bounds__(256) void kD(const unsigned short* __restrict__ vn,
                                          const float* __restrict__ redw,
                                          float* __restrict__ y) {
    __shared__ unsigned short rw_l[64 * 136];  // [o][j-chunk 128 + pad]
    __shared__ unsigned short vl_l[32 * 136];  // [b][j-chunk 128 + pad]

    const int blk = blockIdx.x;
    const int ot = blk & 15;
    const int js = blk >> 4;      // 0..31
    const int o0 = ot * 64;
    const int jb = js * 1024;
    const int tid = threadIdx.x;
    const int lane = tid & 63;
    const int wv = tid >> 6;
    const int quad = lane >> 4;
    const int l15 = lane & 15;

    f4 acc[2];
    acc[0] = (f4){0.f, 0.f, 0.f, 0.f};
    acc[1] = (f4){0.f, 0.f, 0.f, 0.f};

    const int rr0 = tid >> 5, rc0 = tid & 31;  // redw staging
    const int vr0 = tid >> 4, vc0 = tid & 15;  // vn staging
    f4 rwr[8];
    s8 vlr[2];
    auto LOADD = [&](int jc) {
        const int j0 = jb + jc * 128;
#pragma unroll
        for (int i = 0; i < 8; ++i)
            rwr[i] = *(const f4*)(redw + (size_t)(o0 + rr0 + i * 8) * KD + j0 + rc0 * 4);
#pragma unroll
        for (int i = 0; i < 2; ++i)
            vlr[i] = *(const s8*)(vn + (size_t)(vr0 + i * 16) * KD + j0 + vc0 * 8);
    };
    auto STORED = [&]() {
#pragma unroll
        for (int i = 0; i < 8; ++i)
            *(unsigned long long*)(rw_l + (rr0 + i * 8) * 136 + rc0 * 4) =
                pack4(rwr[i][0], rwr[i][1], rwr[i][2], rwr[i][3]);
#pragma unroll
        for (int i = 0; i < 2; ++i)
            *(s8*)(vl_l + (vr0 + i * 16) * 136 + vc0 * 8) = vlr[i];
    };

    LOADD(0);
    for (int jc = 0; jc < 8; ++jc) {
        __syncthreads();
        STORED();
        if (jc < 7) LOADD(jc + 1);
        __syncthreads();
#pragma unroll
        for (int ks = 0; ks < 4; ++ks) {
            const int off = ks * 32 + quad * 8;
            s8 bfr = *(const s8*)(rw_l + (wv * 16 + l15) * 136 + off);
#pragma unroll
            for (int t = 0; t < 2; ++t) {
                s8 af = *(const s8*)(vl_l + (t * 16 + l15) * 136 + off);
                acc[t] = __builtin_amdgcn_mfma_f32_16x16x32_bf16(af, bfr, acc[t], 0, 0, 0);
            }
        }
    }
#pragma unroll
    for (int t = 0; t < 2; ++t)
#pragma unroll
        for (int r = 0; r < 4; ++r) {
            int bq = t * 16 + quad * 4 + r;
            int o = o0 + wv * 16 + l15;
            atomicAdd(&y[(size_t)bq * OUTN + o], acc[t][r]);
        }
}

// ---------------------------------------------------------------------------
// kE: LayerNorm over OUT per b -> d_out. grid 32, block 256.
// ---------------------------------------------------------------------------
__global__ __launch_bounds__(256) void kE(const float* __restrict__ y,
                                          const float* __restrict__ gamma,
                                          const float* __restrict__ beta,
                                          float* __restrict__ out) {
    __shared__ float s1s[4], s2s[4];
    __shared__ float mu_s, rstd_s;

    const int b = blockIdx.x;
    const int tid = threadIdx.x;
    const int wave = tid >> 6;
    const int lane = tid & 63;

    f4 v = *(const f4*)(y + (size_t)b * OUTN + tid * 4);
    float s1 = v[0] + v[1] + v[2] + v[3];
    float s2 = v[0] * v[0] + v[1] * v[1] + v[2] * v[2] + v[3] * v[3];
    for (int off = 32; off > 0; off >>= 1) {
        s1 += __shfl_down(s1, off, 64);
        s2 += __shfl_down(s2, off, 64);
    }
    if (lane == 0) { s1s[wave] = s1; s2s[wave] = s2; }
    __syncthreads();
    if (tid == 0) {
        float S1 = s1s[0] + s1s[1] + s1s[2] + s1s[3];
        float S2 = s2s[0] + s2s[1] + s2s[2] + s2s[3];
        float mu = S1 / (float)OUTN;
        float var = S2 / (float)OUTN - mu * mu;
        mu_s = mu;
        rstd_s = 1.0f / sqrtf(var + 1e-5f);
    }
    __syncthreads();
    const float mu = mu_s, rstd = rstd_s;
    f4 g = *(const f4*)(gamma + tid * 4);
    f4 be = *(const f4*)(beta + tid * 4);
    f4 o;
#pragma unroll
    for (int i = 0; i < 4; ++i) o[i] = (v[i] - mu) * rstd * g[i] + be[i];
    *(f4*)(out + (size_t)b * OUTN + tid * 4) = o;
}

// ---------------------------------------------------------------------------
extern "C" void kernel_launch(void* const* d_in, const int* in_sizes, int n_in,
                              void* d_out, int out_size, void* d_ws, size_t ws_size,
                              hipStream_t stream) {
    const float* x     = (const float*)d_in[0];
    const int*   mask  = (const int*)d_in[1];
    const float* cent  = (const float*)d_in[2];
    const float* convw = (const float*)d_in[3];
    const float* redw  = (const float*)d_in[4];
    const float* gam   = (const float*)d_in[5];
    const float* bet   = (const float*)d_in[6];
    float* out = (float*)d_out;
    char* w = (char*)d_ws;

    unsigned short* assign = (unsigned short*)(w + OFF_ASSIGN);
    float*          vladP  = (float*)(w + OFF_VLADP);
    unsigned short* vn     = (unsigned short*)(w + OFF_VN);
    unsigned short* cwb    = (unsigned short*)(w + OFF_CWB);
    float*          ss     = (float*)(w + OFF_SS);
    float*          asum   = (float*)(w + OFF_ASUM);
    float*          y      = (float*)(w + OFF_Y);

    hipMemsetAsync(asum, 0, 64 * BB * sizeof(float), stream);
    hipMemsetAsync(y, 0, BB * OUTN * sizeof(float), stream);

    kW<<<32, 256, 0, stream>>>(convw, cwb);
    kA<<<BB * 49, 256, 0, stream>>>(x, mask, cwb, assign, asum);
    kB<<<BB * 8 * 4, 256, 0, stream>>>(x, assign, asum, cent, vladP);
    kC1<<<BB * 8, 256, 0, stream>>>(vladP, ss);
    kC2<<<BB * 8, 256, 0, stream>>>(vladP, ss, vn);
    kD<<<16 * 32, 256, 0, stream>>>(vn, redw, y);
    kE<<<BB, 256, 0, stream>>>(y, gam, bet, out);
}

// Round 2
// 446.589 us; speedup vs baseline: 1.2978x; 1.2978x over previous
//
#include <hip/hip_runtime.h>
#include <math.h>

// Problem constants
#define BB 32
#define DD 512
#define TT 64
#define RR 49
#define TR 3136      // TT*RR
#define KK 64
#define OUTN 1024
#define KD 32768     // KK*DD
#define PSTR 1048576ull  // vladP part stride in floats (BB*KK*DD)

typedef float f4 __attribute__((ext_vector_type(4)));
typedef short s8 __attribute__((ext_vector_type(8)));

// Workspace layout (byte offsets, all 256-aligned)
#define OFF_ASSIGN 0ull          // bf16 assign [32][64][3136]    = 12,845,056 B
#define OFF_VLADP  12845056ull   // fp32 vladP [4][32][64][512]   = 16,777,216 B
#define OFF_VN     29622272ull   // bf16 vlad_n [32][32768]       =  2,097,152 B
#define OFF_CWB    31719424ull   // bf16 conv_w [64][512]         =     65,536 B
#define OFF_SS     31784960ull   // fp32 ss [32][64]              =      8,192 B
#define OFF_ASUM   31793152ull   // fp32 asum [32][64]            =      8,192 B
#define OFF_Y      31801344ull   // fp32 y [32][1024]             =    131,072 B
// end: 31,932,416 B (~30.5 MB)

// Cheap fp32->bf16 pack: round-half-up (+0x8000 on bits) then v_perm high-half
// pack. 6 VALU ops per 4 elements vs ~20 for full RNE emulation.
__device__ __forceinline__ unsigned long long pack4(float a, float b, float c, float d) {
    union { float f; unsigned u; } A, B, C, D;
    A.f = a; B.f = b; C.f = c; D.f = d;
    unsigned lo = __builtin_amdgcn_perm(B.u + 0x8000u, A.u + 0x8000u, 0x07060302u);
    unsigned hi = __builtin_amdgcn_perm(D.u + 0x8000u, C.u + 0x8000u, 0x07060302u);
    return (unsigned long long)lo | ((unsigned long long)hi << 32);
}

// ---------------------------------------------------------------------------
// kW: one-time conv_w fp32 -> bf16 convert (shared by all 1568 kA blocks)
// ---------------------------------------------------------------------------
__global__ __launch_bounds__(256) void kW(const float* __restrict__ convw,
                                          unsigned short* __restrict__ cwb) {
    int idx = blockIdx.x * 256 + threadIdx.x;   // 8192 f4's total
    f4 v = *(const f4*)(convw + idx * 4);
    *(unsigned long long*)(cwb + idx * 4) = pack4(v[0], v[1], v[2], v[3]);
}

// ---------------------------------------------------------------------------
// kA: logits = conv_w @ x (MFMA bf16), softmax over k, mask, asum, assign(bf16)
// grid 32*49, block 256. Per block: 64 k x 64 p, K-loop over d=512.
// v3: round-0 staging structure (short register live ranges — the v2 register
// pipeline spilled to scratch: VGPR=76 with 64+ live regs, VALUBusy 12->56%).
// A-fragments come straight from L2-hot bf16 global (kW prepass) — deletes the
// conv_w LDS staging (half the staging work, -17KB LDS -> 4 blocks/CU).
// ---------------------------------------------------------------------------
__global__ __launch_bounds__(256) void kA(const float* __restrict__ x,
                                          const int* __restrict__ mask,
                                          const unsigned short* __restrict__ cwb,
                                          unsigned short* __restrict__ assign,
                                          float* __restrict__ asum) {
    __shared__ unsigned short xT_l[64 * 136];  // [p][d-chunk 128 + pad]
    __shared__ float sm[64 * 68];              // [k][p] logits/assign
    __shared__ float redM[256], redS[256];     // softmax reduce buffers

    const int blk = blockIdx.x;
    const int b = blk / 49;
    const int pc = blk % 49;
    const int p0 = pc * 64;
    const int tid = threadIdx.x;
    const int lane = tid & 63;
    const int wv = tid >> 6;
    const int quad = lane >> 4;
    const int l15 = lane & 15;

    f4 acc[4];
#pragma unroll
    for (int t = 0; t < 4; ++t) acc[t] = (f4){0.f, 0.f, 0.f, 0.f};

    const float* xb = x + (size_t)b * DD * TR;
    const unsigned short* cwrow = cwb + (wv * 16 + l15) * DD + quad * 8;

    for (int dc = 0; dc < 4; ++dc) {
        const int d0 = dc * 128;
        // A-frags for this chunk: 4 x s8 from L2-hot bf16 global; issued before
        // the barrier so the latency overlaps the staging below.
        s8 af[4];
#pragma unroll
        for (int ks = 0; ks < 4; ++ks) af[ks] = *(const s8*)(cwrow + d0 + ks * 32);
        __syncthreads();
        // stage x chunk transposed [64 p][128 d]: thread = (d-quad, p-quad)
#pragma unroll
        for (int i = 0; i < 2; ++i) {
            int lin = i * 256 + tid;
            int dq = lin >> 4;   // 0..31 -> d = d0 + dq*4
            int pq = lin & 15;
            const float* xp = xb + (size_t)(d0 + dq * 4) * TR + p0 + pq * 4;
            f4 a0 = *(const f4*)(xp);
            f4 a1 = *(const f4*)(xp + TR);
            f4 a2 = *(const f4*)(xp + 2 * TR);
            f4 a3 = *(const f4*)(xp + 3 * TR);
#pragma unroll
            for (int jj = 0; jj < 4; ++jj) {
                int j = (jj + pq) & 3;  // stagger to spread banks
                *(unsigned long long*)(xT_l + (pq * 4 + j) * 136 + dq * 4) =
                    pack4(a0[j], a1[j], a2[j], a3[j]);
            }
        }
        __syncthreads();
#pragma unroll
        for (int ks = 0; ks < 4; ++ks) {
            int off = ks * 32 + quad * 8;
#pragma unroll
            for (int t = 0; t < 4; ++t) {
                s8 bfr = *(const s8*)(xT_l + (t * 16 + l15) * 136 + off);
                acc[t] = __builtin_amdgcn_mfma_f32_16x16x32_bf16(af[ks], bfr, acc[t], 0, 0, 0);
            }
        }
    }
    // dump C/D frags to sm[k][p]: col=lane&15 (p), row=quad*4+reg (k)
#pragma unroll
    for (int t = 0; t < 4; ++t)
#pragma unroll
        for (int r = 0; r < 4; ++r)
            sm[(wv * 16 + quad * 4 + r) * 68 + t * 16 + l15] = acc[t][r];
    __syncthreads();

    // parallel softmax over k per column p: wave wv owns k in [wv*16, wv*16+16)
    const int p = lane;
    float mx = -1e30f;
#pragma unroll
    for (int i = 0; i < 16; ++i) mx = fmaxf(mx, sm[(wv * 16 + i) * 68 + p]);
    redM[wv * 64 + p] = mx;
    __syncthreads();
    mx = fmaxf(fmaxf(redM[p], redM[64 + p]), fmaxf(redM[128 + p], redM[192 + p]));
    float s = 0.f;
#pragma unroll
    for (int i = 0; i < 16; ++i) {
        float e = __expf(sm[(wv * 16 + i) * 68 + p] - mx);
        sm[(wv * 16 + i) * 68 + p] = e;
        s += e;
    }
    redS[wv * 64 + p] = s;
    __syncthreads();
    float tot = redS[p] + redS[64 + p] + redS[128 + p] + redS[192 + p];
    const int tt = (p0 + p) / RR;
    const float inv = (float)mask[b * TT + tt] / tot;
    // scale + per-k wave-reduced asum
#pragma unroll
    for (int i = 0; i < 16; ++i) {
        float v = sm[(wv * 16 + i) * 68 + p] * inv;
        sm[(wv * 16 + i) * 68 + p] = v;
        float r = v;
#pragma unroll
        for (int off = 32; off > 0; off >>= 1) r += __shfl_down(r, off, 64);
        if (lane == 0) atomicAdd(&asum[b * 64 + wv * 16 + i], r);
    }
    __syncthreads();
    // write assign bf16 [k][p]
#pragma unroll
    for (int i = 0; i < 4; ++i) {
        int lin = i * 256 + tid;
        int kr = lin >> 4;
        int pqq = lin & 15;
        f4 v = *(const f4*)(sm + kr * 68 + pqq * 4);
        *(unsigned long long*)(assign + (size_t)(b * 64 + kr) * TR + p0 + pqq * 4) =
            pack4(v[0], v[1], v[2], v[3]);
    }
}

// ---------------------------------------------------------------------------
// kB: vladP[ph][b,k,d] = sum_{p in quarter} assign[k][p]*x[d][p]  (MFMA bf16)
// part 0 additionally subtracts asum*centroid. grid 32*8*4, block 256.
// Load-ahead pipeline (static-indexed regs — safe from scratch demotion).
// ---------------------------------------------------------------------------
__global__ __launch_bounds__(256) void kB(const float* __restrict__ x,
                                          const unsigned short* __restrict__ assign,
                                          const float* __restrict__ asum,
                                          const float* __restrict__ cent,
                                          float* __restrict__ vladP) {
    __shared__ unsigned short as_l[64 * 72];  // [k][p-chunk 64 + pad]
    __shared__ unsigned short x_l[64 * 72];   // [d][p-chunk 64 + pad]

    const int blk = blockIdx.x;
    const int b  = blk >> 5;
    const int ds = (blk >> 2) & 7;
    const int ph = blk & 3;
    const int d0 = ds * 64;
    const int tid = threadIdx.x;
    const int lane = tid & 63;
    const int wv = tid >> 6;
    const int quad = lane >> 4;
    const int l15 = lane & 15;

    f4 acc[4];
#pragma unroll
    for (int t = 0; t < 4; ++t) acc[t] = (f4){0.f, 0.f, 0.f, 0.f};

    const int pcs = (ph * 49) >> 2;        // 0,12,24,36
    const int pce = ((ph + 1) * 49) >> 2;  // 12,24,36,49

    const int ar0 = tid >> 3, ac0 = tid & 7;   // assign staging
    const int xr0 = tid >> 4, xc0 = tid & 15;  // x staging

    s8 asr[2];
    f4 xrr[4];
    auto LOADB = [&](int pc) {
        const int pp = pc * 64;
#pragma unroll
        for (int i = 0; i < 2; ++i)
            asr[i] = *(const s8*)(assign + (size_t)(b * 64 + ar0 + i * 32) * TR + pp + ac0 * 8);
#pragma unroll
        for (int i = 0; i < 4; ++i)
            xrr[i] = *(const f4*)(x + (size_t)(b * DD + d0 + xr0 + i * 16) * TR + pp + xc0 * 4);
    };
    auto STOREB = [&]() {
#pragma unroll
        for (int i = 0; i < 2; ++i)
            *(s8*)(as_l + (ar0 + i * 32) * 72 + ac0 * 8) = asr[i];
#pragma unroll
        for (int i = 0; i < 4; ++i)
            *(unsigned long long*)(x_l + (xr0 + i * 16) * 72 + xc0 * 4) =
                pack4(xrr[i][0], xrr[i][1], xrr[i][2], xrr[i][3]);
    };

    LOADB(pcs);
    for (int pc = pcs; pc < pce; ++pc) {
        __syncthreads();
        STOREB();
        if (pc + 1 < pce) LOADB(pc + 1);   // next-tile loads fly over MFMA phase
        __syncthreads();
#pragma unroll
        for (int ks = 0; ks < 2; ++ks) {
            const int off = ks * 32 + quad * 8;
            s8 af = *(const s8*)(as_l + (wv * 16 + l15) * 72 + off);
#pragma unroll
            for (int t = 0; t < 4; ++t) {
                s8 bfr = *(const s8*)(x_l + (t * 16 + l15) * 72 + off);
                acc[t] = __builtin_amdgcn_mfma_f32_16x16x32_bf16(af, bfr, acc[t], 0, 0, 0);
            }
        }
    }
    float* vp = vladP + (size_t)ph * PSTR;
#pragma unroll
    for (int r = 0; r < 4; ++r) {
        const int k = wv * 16 + quad * 4 + r;
        float corr = (ph == 0) ? asum[b * 64 + k] : 0.f;
#pragma unroll
        for (int t = 0; t < 4; ++t) {
            const int d = d0 + t * 16 + l15;
            float v = acc[t][r];
            if (ph == 0) v -= corr * cent[k * DD + d];
            vp[(size_t)(b * 64 + k) * DD + d] = v;
        }
    }
}

// ---------------------------------------------------------------------------
// kC1: per-row sum of squares of (P0+P1+P2+P3). grid 32*8, block 256.
// ---------------------------------------------------------------------------
__global__ __launch_bounds__(256) void kC1(const float* __restrict__ vladP,
                                           float* __restrict__ ss) {
    const int blk = blockIdx.x;
    const int b = blk >> 3;
    const int ks = blk & 7;
    const int tid = threadIdx.x;
    const int kr = tid >> 5;
    const int l32 = tid & 31;
    const int k = ks * 8 + kr;
    const float* q = vladP + (size_t)(b * 64 + k) * DD;
    float s = 0.f;
#pragma unroll
    for (int i = 0; i < 4; ++i) {
        f4 a0 = *(const f4*)(q + i * 128 + l32 * 4);
        f4 a1 = *(const f4*)(q + PSTR + i * 128 + l32 * 4);
        f4 a2 = *(const f4*)(q + 2 * PSTR + i * 128 + l32 * 4);
        f4 a3 = *(const f4*)(q + 3 * PSTR + i * 128 + l32 * 4);
#pragma unroll
        for (int j = 0; j < 4; ++j) {
            float v = (a0[j] + a1[j]) + (a2[j] + a3[j]);
            s = fmaf(v, v, s);
        }
    }
    for (int off = 16; off > 0; off >>= 1) s += __shfl_down(s, off, 32);
    if (l32 == 0) ss[b * 64 + k] = s;
}

// ---------------------------------------------------------------------------
// kC2: scales = intra*global norm; write vlad_n bf16. grid 32*8, block 256.
// ---------------------------------------------------------------------------
__global__ __launch_bounds__(256) void kC2(const float* __restrict__ vladP,
                                           const float* __restrict__ ss,
                                           unsigned short* __restrict__ vn) {
    __shared__ float sc[64];
    const int blk = blockIdx.x;
    const int b = blk >> 3;
    const int js = blk & 7;
    const int tid = threadIdx.x;
    if (tid < 64) {
        float rn = sqrtf(ss[b * 64 + tid]);
        float inv = 1.f / fmaxf(rn, 1e-12f);
        float cb = rn * inv; cb = cb * cb;
        float g = cb;
        for (int off = 32; off > 0; off >>= 1) g += __shfl_down(g, off, 64);
        g = __shfl(g, 0, 64);
        float gi = 1.f / fmaxf(sqrtf(g), 1e-12f);
        sc[tid] = inv * gi;
    }
    __syncthreads();
    const float* q = vladP + (size_t)b * KD;
#pragma unroll
    for (int it = 0; it < 4; ++it) {
        int j = js * 4096 + it * 1024 + tid * 4;
        f4 a0 = *(const f4*)(q + j);
        f4 a1 = *(const f4*)(q + PSTR + j);
        f4 a2 = *(const f4*)(q + 2 * PSTR + j);
        f4 a3 = *(const f4*)(q + 3 * PSTR + j);
        float scl = sc[j >> 9];
        *(unsigned long long*)(vn + (size_t)b * KD + j) =
            pack4(((a0[0] + a1[0]) + (a2[0] + a3[0])) * scl,
                  ((a0[1] + a1[1]) + (a2[1] + a3[1])) * scl,
                  ((a0[2] + a1[2]) + (a2[2] + a3[2])) * scl,
                  ((a0[3] + a1[3]) + (a2[3] + a3[3])) * scl);
    }
}

// ---------------------------------------------------------------------------
// kD: y[b,o] += vlad_n @ red_w^T (MFMA bf16). grid 16 o-tiles * 32 j-splits,
// block 256. LDS 26KB; static-indexed load-ahead pipeline.
// ---------------------------------------------------------------------------
__global__ __launch_bounds__(256) void kD(const unsigned short* __restrict__ vn,
                                          const float* __restrict__ redw,
                                          float* __restrict__ y) {
    __shared__ unsigned short rw_l[64 * 136];  // [o][j-chunk 128 + pad]
    __shared__ unsigned short vl_l[32 * 136];  // [b][j-chunk 128 + pad]

    const int blk = blockIdx.x;
    const int ot = blk & 15;
    const int js = blk >> 4;      // 0..31
    const int o0 = ot * 64;
    const int jb = js * 1024;
    const int tid = threadIdx.x;
    const int lane = tid & 63;
    const int wv = tid >> 6;
    const int quad = lane >> 4;
    const int l15 = lane & 15;

    f4 acc[2];
    acc[0] = (f4){0.f, 0.f, 0.f, 0.f};
    acc[1] = (f4){0.f, 0.f, 0.f, 0.f};

    const int rr0 = tid >> 5, rc0 = tid & 31;  // redw staging
    const int vr0 = tid >> 4, vc0 = tid & 15;  // vn staging
    f4 rwr[8];
    s8 vlr[2];
    auto LOADD = [&](int jc) {
        const int j0 = jb + jc * 128;
#pragma unroll
        for (int i = 0; i < 8; ++i)
            rwr[i] = *(const f4*)(redw + (size_t)(o0 + rr0 + i * 8) * KD + j0 + rc0 * 4);
#pragma unroll
        for (int i = 0; i < 2; ++i)
            vlr[i] = *(const s8*)(vn + (size_t)(vr0 + i * 16) * KD + j0 + vc0 * 8);
    };
    auto STORED = [&]() {
#pragma unroll
        for (int i = 0; i < 8; ++i)
            *(unsigned long long*)(rw_l + (rr0 + i * 8) * 136 + rc0 * 4) =
                pack4(rwr[i][0], rwr[i][1], rwr[i][2], rwr[i][3]);
#pragma unroll
        for (int i = 0; i < 2; ++i)
            *(s8*)(vl_l + (vr0 + i * 16) * 136 + vc0 * 8) = vlr[i];
    };

    LOADD(0);
    for (int jc = 0; jc < 8; ++jc) {
        __syncthreads();
        STORED();
        if (jc < 7) LOADD(jc + 1);
        __syncthreads();
#pragma unroll
        for (int ks = 0; ks < 4; ++ks) {
            const int off = ks * 32 + quad * 8;
            s8 bfr = *(const s8*)(rw_l + (wv * 16 + l15) * 136 + off);
#pragma unroll
            for (int t = 0; t < 2; ++t) {
                s8 af = *(const s8*)(vl_l + (t * 16 + l15) * 136 + off);
                acc[t] = __builtin_amdgcn_mfma_f32_16x16x32_bf16(af, bfr, acc[t], 0, 0, 0);
            }
        }
    }
#pragma unroll
    for (int t = 0; t < 2; ++t)
#pragma unroll
        for (int r = 0; r < 4; ++r) {
            int bq = t * 16 + quad * 4 + r;
            int o = o0 + wv * 16 + l15;
            atomicAdd(&y[(size_t)bq * OUTN + o], acc[t][r]);
        }
}

// ---------------------------------------------------------------------------
// kE: LayerNorm over OUT per b -> d_out. grid 32, block 256.
// ---------------------------------------------------------------------------
__global__ __launch_bounds__(256) void kE(const float* __restrict__ y,
                                          const float* __restrict__ gamma,
                                          const float* __restrict__ beta,
                                          float* __restrict__ out) {
    __shared__ float s1s[4], s2s[4];
    __shared__ float mu_s, rstd_s;

    const int b = blockIdx.x;
    const int tid = threadIdx.x;
    const int wave = tid >> 6;
    const int lane = tid & 63;

    f4 v = *(const f4*)(y + (size_t)b * OUTN + tid * 4);
    float s1 = v[0] + v[1] + v[2] + v[3];
    float s2 = v[0] * v[0] + v[1] * v[1] + v[2] * v[2] + v[3] * v[3];
    for (int off = 32; off > 0; off >>= 1) {
        s1 += __shfl_down(s1, off, 64);
        s2 += __shfl_down(s2, off, 64);
    }
    if (lane == 0) { s1s[wave] = s1; s2s[wave] = s2; }
    __syncthreads();
    if (tid == 0) {
        float S1 = s1s[0] + s1s[1] + s1s[2] + s1s[3];
        float S2 = s2s[0] + s2s[1] + s2s[2] + s2s[3];
        float mu = S1 / (float)OUTN;
        float var = S2 / (float)OUTN - mu * mu;
        mu_s = mu;
        rstd_s = 1.0f / sqrtf(var + 1e-5f);
    }
    __syncthreads();
    const float mu = mu_s, rstd = rstd_s;
    f4 g = *(const f4*)(gamma + tid * 4);
    f4 be = *(const f4*)(beta + tid * 4);
    f4 o;
#pragma unroll
    for (int i = 0; i < 4; ++i) o[i] = (v[i] - mu) * rstd * g[i] + be[i];
    *(f4*)(out + (size_t)b * OUTN + tid * 4) = o;
}

// ---------------------------------------------------------------------------
extern "C" void kernel_launch(void* const* d_in, const int* in_sizes, int n_in,
                              void* d_out, int out_size, void* d_ws, size_t ws_size,
                              hipStream_t stream) {
    const float* x     = (const float*)d_in[0];
    const int*   mask  = (const int*)d_in[1];
    const float* cent  = (const float*)d_in[2];
    const float* convw = (const float*)d_in[3];
    const float* redw  = (const float*)d_in[4];
    const float* gam   = (const float*)d_in[5];
    const float* bet   = (const float*)d_in[6];
    float* out = (float*)d_out;
    char* w = (char*)d_ws;

    unsigned short* assign = (unsigned short*)(w + OFF_ASSIGN);
    float*          vladP  = (float*)(w + OFF_VLADP);
    unsigned short* vn     = (unsigned short*)(w + OFF_VN);
    unsigned short* cwb    = (unsigned short*)(w + OFF_CWB);
    float*          ss     = (float*)(w + OFF_SS);
    float*          asum   = (float*)(w + OFF_ASUM);
    float*          y      = (float*)(w + OFF_Y);

    hipMemsetAsync(asum, 0, 64 * BB * sizeof(float), stream);
    hipMemsetAsync(y, 0, BB * OUTN * sizeof(float), stream);

    kW<<<32, 256, 0, stream>>>(convw, cwb);
    kA<<<BB * 49, 256, 0, stream>>>(x, mask, cwb, assign, asum);
    kB<<<BB * 8 * 4, 256, 0, stream>>>(x, assign, asum, cent, vladP);
    kC1<<<BB * 8, 256, 0, stream>>>(vladP, ss);
    kC2<<<BB * 8, 256, 0, stream>>>(vladP, ss, vn);
    kD<<<16 * 32, 256, 0, stream>>>(vn, redw, y);
    kE<<<BB, 256, 0, stream>>>(y, gam, bet, out);
}